// Round 1
// baseline (216.363 us; speedup 1.0000x reference)
//
#include <hip/hip_runtime.h>
#include <hip/hip_bf16.h>

// Problem constants (from reference)
#define BATCH   16384
#define C_SEL   32
#define C_TOTAL 64
#define IN_F    128
#define OUT_F   128

#define BM      128   // batch rows per block
#define LDW     136   // LDS row stride (bf16 elems): +8 pad keeps 16B align, spreads banks

typedef __bf16 bf16x8 __attribute__((ext_vector_type(8)));
typedef __bf16 bf16x4 __attribute__((ext_vector_type(4)));
typedef float  f32x4  __attribute__((ext_vector_type(4)));

__global__ __launch_bounds__(256) void pl_mfma_kernel(
    const float* __restrict__ inp,       // (BATCH, C_SEL, IN_F)
    const float* __restrict__ weight,    // (C_TOTAL, OUT_F, IN_F)
    const float* __restrict__ bias,      // (C_TOTAL, OUT_F)
    const int*   __restrict__ channels,  // (C_SEL,)
    float*       __restrict__ out)       // (BATCH, C_SEL, OUT_F)
{
    __shared__ __bf16 ldsW[OUT_F * LDW];   // 128*136*2 = 34.8 KB

    const int gx = blockIdx.x;
    const int c  = gx >> 7;            // channel index 0..31 (128 mtiles per channel)
    const int m0 = (gx & 127) * BM;    // batch tile start

    const int ch = channels[c];        // uniform scalar load

    const int t  = threadIdx.x;
    const int w  = t >> 6;             // wave 0..3 -> rows [w*32, w*32+32)
    const int l  = t & 63;
    const int lr = l & 15;             // fragment row (A) / col (B)
    const int lg = l >> 4;             // k-group 0..3

    // ---- A fragments: direct global -> reg, fp32 -> bf16 (each byte read once) ----
    bf16x8 afrag[2][4];
    #pragma unroll
    for (int mt = 0; mt < 2; ++mt) {
        const size_t m = (size_t)(m0 + w * 32 + mt * 16 + lr);
        const float* arow = inp + (m * C_SEL + (size_t)c) * IN_F;
        #pragma unroll
        for (int ks = 0; ks < 4; ++ks) {
            const float* p = arow + ks * 32 + lg * 8;
            const float4 f0 = *reinterpret_cast<const float4*>(p);
            const float4 f1 = *reinterpret_cast<const float4*>(p + 4);
            bf16x8 a;
            a[0] = (__bf16)f0.x; a[1] = (__bf16)f0.y; a[2] = (__bf16)f0.z; a[3] = (__bf16)f0.w;
            a[4] = (__bf16)f1.x; a[5] = (__bf16)f1.y; a[6] = (__bf16)f1.z; a[7] = (__bf16)f1.w;
            afrag[mt][ks] = a;
        }
    }

    // ---- stage W[ch] fp32 -> bf16 into LDS (coalesced float4 loads) ----
    const float* wsrc = weight + (size_t)ch * (OUT_F * IN_F);
    #pragma unroll
    for (int i = 0; i < 16; ++i) {
        const int fidx = i * 1024 + t * 4;      // 256 thr * 4 floats = 1024/iter
        const int row  = fidx >> 7;
        const int col  = fidx & 127;
        const float4 f = *reinterpret_cast<const float4*>(wsrc + fidx);
        bf16x4 v;
        v[0] = (__bf16)f.x; v[1] = (__bf16)f.y; v[2] = (__bf16)f.z; v[3] = (__bf16)f.w;
        *reinterpret_cast<bf16x4*>(&ldsW[row * LDW + col]) = v;   // 8B ds_write
    }
    __syncthreads();

    // ---- MFMA main: out[m][o] = sum_k A[m][k] * W[o][k] ----
    f32x4 acc[2][8];
    #pragma unroll
    for (int mt = 0; mt < 2; ++mt)
        #pragma unroll
        for (int nt = 0; nt < 8; ++nt) {
            f32x4 z = {0.f, 0.f, 0.f, 0.f};
            acc[mt][nt] = z;
        }

    #pragma unroll
    for (int ks = 0; ks < 4; ++ks) {
        #pragma unroll
        for (int nt = 0; nt < 8; ++nt) {
            // B operand: lane holds col o = nt*16+lr, k = ks*32 + lg*8 .. +7 (contiguous 16B)
            const bf16x8 b = *reinterpret_cast<const bf16x8*>(
                &ldsW[(nt * 16 + lr) * LDW + ks * 32 + lg * 8]);
            acc[0][nt] = __builtin_amdgcn_mfma_f32_16x16x32_bf16(afrag[0][ks], b, acc[0][nt], 0, 0, 0);
            acc[1][nt] = __builtin_amdgcn_mfma_f32_16x16x32_bf16(afrag[1][ks], b, acc[1][nt], 0, 0, 0);
        }
    }

    // ---- epilogue: bias + store (D layout: col = lane&15, row = lg*4 + reg) ----
    const float* brow = bias + (size_t)ch * OUT_F;
    #pragma unroll
    for (int nt = 0; nt < 8; ++nt) {
        const float bv = brow[nt * 16 + lr];
        #pragma unroll
        for (int mt = 0; mt < 2; ++mt) {
            const size_t mbase = (size_t)(m0 + w * 32 + mt * 16 + lg * 4);
            #pragma unroll
            for (int j = 0; j < 4; ++j) {
                const size_t m = mbase + j;
                out[(m * C_SEL + (size_t)c) * OUT_F + nt * 16 + lr] = acc[mt][nt][j] + bv;
            }
        }
    }
}

extern "C" void kernel_launch(void* const* d_in, const int* in_sizes, int n_in,
                              void* d_out, int out_size, void* d_ws, size_t ws_size,
                              hipStream_t stream) {
    const float* inp      = (const float*)d_in[0];
    const float* weight   = (const float*)d_in[1];
    const float* bias     = (const float*)d_in[2];
    const int*   channels = (const int*)d_in[3];
    float*       out      = (float*)d_out;

    dim3 grid(C_SEL * (BATCH / BM));   // 32 * 128 = 4096 blocks
    dim3 block(256);
    pl_mfma_kernel<<<grid, block, 0, stream>>>(inp, weight, bias, channels, out);
}

// Round 2
// 142.089 us; speedup vs baseline: 1.5227x; 1.5227x over previous
//
#include <hip/hip_runtime.h>
#include <hip/hip_bf16.h>

// Problem constants (from reference)
#define BATCH   16384
#define C_SEL   32
#define C_TOTAL 64
#define IN_F    128
#define OUT_F   128

#define BM      128   // batch rows per block

typedef __bf16 bf16x8 __attribute__((ext_vector_type(8)));
typedef float  f32x4  __attribute__((ext_vector_type(4)));

__global__ __launch_bounds__(256) void pl_mfma_kernel(
    const float* __restrict__ inp,       // (BATCH, C_SEL, IN_F)
    const float* __restrict__ weight,    // (C_TOTAL, OUT_F, IN_F)
    const float* __restrict__ bias,      // (C_TOTAL, OUT_F)
    const int*   __restrict__ channels,  // (C_SEL,)
    float*       __restrict__ out)       // (BATCH, C_SEL, OUT_F)
{
    // 128 rows x 128 cols bf16, row stride 128 (exactly 32 KB -> 5 blocks/CU).
    // Bank-conflict-free via 16B-unit XOR swizzle: unit' = unit ^ (row & 7).
    __shared__ __bf16 ldsW[OUT_F * IN_F];

    const int gx = blockIdx.x;
    const int c  = gx & 31;            // channel fastest: co-resident blocks stream
    const int m0 = (gx >> 5) * BM;     // contiguous input/output regions

    const int ch = channels[c];        // uniform scalar load

    const int t  = threadIdx.x;
    const int w  = t >> 6;             // wave 0..3 -> rows [w*32, w*32+32)
    const int l  = t & 63;
    const int lr = l & 15;             // fragment row (A) / col (B)
    const int lg = l >> 4;             // k-group 0..3

    // ---- A fragments: direct global -> reg, fp32 -> bf16 (each byte read once) ----
    bf16x8 afrag[2][4];
    #pragma unroll
    for (int mt = 0; mt < 2; ++mt) {
        const size_t m = (size_t)(m0 + w * 32 + mt * 16 + lr);
        const float* arow = inp + (m * C_SEL + (size_t)c) * IN_F;
        #pragma unroll
        for (int ks = 0; ks < 4; ++ks) {
            const float* p = arow + ks * 32 + lg * 8;
            const float4 f0 = *reinterpret_cast<const float4*>(p);
            const float4 f1 = *reinterpret_cast<const float4*>(p + 4);
            bf16x8 a;
            a[0] = (__bf16)f0.x; a[1] = (__bf16)f0.y; a[2] = (__bf16)f0.z; a[3] = (__bf16)f0.w;
            a[4] = (__bf16)f1.x; a[5] = (__bf16)f1.y; a[6] = (__bf16)f1.z; a[7] = (__bf16)f1.w;
            afrag[mt][ks] = a;
        }
    }

    // ---- stage W[ch] fp32 -> bf16 into LDS (swizzled 16B units) ----
    const float* wsrc = weight + (size_t)ch * (OUT_F * IN_F);
    #pragma unroll
    for (int i = 0; i < 8; ++i) {
        const int fidx = i * 2048 + t * 8;      // 256 thr * 8 floats = 2048/iter
        const int row  = fidx >> 7;
        const int u    = (fidx & 127) >> 3;     // 16B unit within row (0..15)
        const float4 f0 = *reinterpret_cast<const float4*>(wsrc + fidx);
        const float4 f1 = *reinterpret_cast<const float4*>(wsrc + fidx + 4);
        bf16x8 v;
        v[0] = (__bf16)f0.x; v[1] = (__bf16)f0.y; v[2] = (__bf16)f0.z; v[3] = (__bf16)f0.w;
        v[4] = (__bf16)f1.x; v[5] = (__bf16)f1.y; v[6] = (__bf16)f1.z; v[7] = (__bf16)f1.w;
        const int up = u ^ (row & 7);
        *reinterpret_cast<bf16x8*>(&ldsW[row * IN_F + up * 8]) = v;
    }
    __syncthreads();

    // ---- MFMA main: out[m][o] = sum_k A[m][k] * W[o][k] ----
    f32x4 acc[2][8];
    #pragma unroll
    for (int mt = 0; mt < 2; ++mt)
        #pragma unroll
        for (int nt = 0; nt < 8; ++nt) {
            f32x4 z = {0.f, 0.f, 0.f, 0.f};
            acc[mt][nt] = z;
        }

    #pragma unroll
    for (int ks = 0; ks < 4; ++ks) {
        #pragma unroll
        for (int nt = 0; nt < 8; ++nt) {
            const int row = nt * 16 + lr;               // B col = out feature
            const int u   = (ks * 4 + lg) ^ (lr & 7);   // swizzled 16B unit
            const bf16x8 b = *reinterpret_cast<const bf16x8*>(
                &ldsW[row * IN_F + u * 8]);
            acc[0][nt] = __builtin_amdgcn_mfma_f32_16x16x32_bf16(afrag[0][ks], b, acc[0][nt], 0, 0, 0);
            acc[1][nt] = __builtin_amdgcn_mfma_f32_16x16x32_bf16(afrag[1][ks], b, acc[1][nt], 0, 0, 0);
        }
    }

    // ---- epilogue: bias + store (D layout: col = lane&15, row = lg*4 + reg) ----
    const float* brow = bias + (size_t)ch * OUT_F;
    #pragma unroll
    for (int mt = 0; mt < 2; ++mt) {
        #pragma unroll
        for (int j = 0; j < 4; ++j) {
            const size_t m = (size_t)(m0 + w * 32 + mt * 16 + lg * 4 + j);
            float* orow = out + (m * C_SEL + (size_t)c) * OUT_F;
            #pragma unroll
            for (int nt = 0; nt < 8; ++nt) {
                orow[nt * 16 + lr] = acc[mt][nt][j] + brow[nt * 16 + lr];
            }
        }
    }
}

extern "C" void kernel_launch(void* const* d_in, const int* in_sizes, int n_in,
                              void* d_out, int out_size, void* d_ws, size_t ws_size,
                              hipStream_t stream) {
    const float* inp      = (const float*)d_in[0];
    const float* weight   = (const float*)d_in[1];
    const float* bias     = (const float*)d_in[2];
    const int*   channels = (const int*)d_in[3];
    float*       out      = (float*)d_out;

    dim3 grid(C_SEL * (BATCH / BM));   // 4096 blocks, channel-fastest
    dim3 block(256);
    pl_mfma_kernel<<<grid, block, 0, stream>>>(inp, weight, bias, channels, out);
}